// Round 7
// baseline (367.024 us; speedup 1.0000x reference)
//
#include <hip/hip_runtime.h>

#define BB 64
#define TT 1024
#define BT (BB * TT)
#define HH 512
#define KMIX 10
#define UU 64
#define VV 80
#define SDIM 3
#define OUTW 595
#define ROWS 16

// ---------------- kW: transpose W [512,30] -> Wt [30,512] (tiny, once) ----------------
__global__ __launch_bounds__(256) void kW_transpose(const float* __restrict__ Wm, float* __restrict__ Wt) {
    int idx = blockIdx.x * 256 + threadIdx.x;
    if (idx < 30 * HH) {
        int j = idx >> 9, h = idx & 511;
        Wt[idx] = Wm[h * 30 + j];
    }
}

// ---------------- k1: abk_t = exp(X@Wt^T + b) transposed [30][BT]; fused x/stroke copy ----------------
// 256 thr, 4 blocks/CU. GEMM thread = (hc 0..15, jp 0..14): one x-read feeds TWO j columns (LDS reads halved).
__global__ __launch_bounds__(256) void k1_gemm(
    const float* __restrict__ x,       // [BT, H]
    const float* __restrict__ stroke,  // [BT, 3]
    const float* __restrict__ Wt,      // [30, 512]
    const float* __restrict__ bias,    // [30]
    float* __restrict__ out,           // [BT, 595]
    float* __restrict__ abk_t)         // [30, BT]
{
    __shared__ float xs[ROWS][HH + 4];  // 33 KB; reused for partials
    const int tid = threadIdx.x;
    const int r0 = blockIdx.x * ROWS;

    // Stage X tile (2048 float4, 8 per thread)
    const float4* x4 = (const float4*)(x + (size_t)r0 * HH);
    #pragma unroll
    for (int i = 0; i < 8; ++i) {
        int f4 = tid + (i << 8);
        *(float4*)&xs[f4 >> 7][(f4 & 127) << 2] = x4[f4];
    }
    if (tid < ROWS * SDIM) {
        int row = tid / SDIM, c = tid % SDIM;
        out[(size_t)(r0 + row) * OUTW + HH + VV + c] = stroke[(size_t)(r0 + row) * SDIM + c];
    }
    __syncthreads();

    // Coalesced x-part copy via LDS (measured better than 16B-stride register stores: R3 103 vs R5 111 us)
    #pragma unroll
    for (int i = 0; i < 32; ++i) {
        int idx = tid + (i << 8);
        out[(size_t)(r0 + (idx >> 9)) * OUTW + (idx & 511)] = xs[idx >> 9][idx & 511];
    }

    // GEMM partials: thread = (hc, jp): W cols 2jp,2jp+1 over h-chunk hc*32..+31, all 16 rows.
    const bool active = tid < 240;
    float acc0[ROWS], acc1[ROWS];
    if (active) {
        int hc = tid / 15, jp = tid % 15;
        const float4* wp0 = (const float4*)(Wt + (2 * jp) * HH + hc * 32);
        const float4* wp1 = (const float4*)(Wt + (2 * jp + 1) * HH + hc * 32);
        float4 w0[8], w1[8];
        #pragma unroll
        for (int q = 0; q < 8; ++q) { w0[q] = wp0[q]; w1[q] = wp1[q]; }
        #pragma unroll
        for (int r = 0; r < ROWS; ++r) {
            const float4* xp = (const float4*)&xs[r][(tid / 15) * 32];  // 15 lanes broadcast same addr
            float s0 = 0.f, s1 = 0.f;
            #pragma unroll
            for (int q = 0; q < 8; ++q) {
                float4 xv = xp[q];
                s0 += xv.x * w0[q].x + xv.y * w0[q].y + xv.z * w0[q].z + xv.w * w0[q].w;
                s1 += xv.x * w1[q].x + xv.y * w1[q].y + xv.z * w1[q].z + xv.w * w1[q].w;
            }
            acc0[r] = s0; acc1[r] = s1;
        }
    }
    __syncthreads();                 // xs reads done -> reuse as partial buffer
    float* plds = &xs[0][0];         // layout [hc][r][j] = hc*480 + r*30 + j
    if (active) {
        int hc = tid / 15, jp = tid % 15;
        #pragma unroll
        for (int r = 0; r < ROWS; ++r) {
            // float2 store at even offset; lanes: +2 floats per jp -> ~5-way max on 16 instrs (minor)
            *(float2*)&plds[hc * 480 + r * 30 + 2 * jp] = make_float2(acc0[r], acc1[r]);
        }
    }
    __syncthreads();
    // Reduce over hc: e=(jj,row); read banks: (30*row+jj) mod 32 -> uniform 2 lanes/bank (free)
    for (int e = tid; e < 480; e += 256) {
        int row = e & 15, jj = e >> 4;
        float s = 0.f;
        #pragma unroll
        for (int q = 0; q < 16; ++q) s += plds[q * 480 + row * 30 + jj];
        abk_t[(size_t)jj * BT + r0 + row] = expf(s + bias[jj]);  // 16 consecutive floats per jj-group
    }
}

// ---------------- k23: fused scan (redundant per quarter) + phi + window ----------------
// Block = (b, quarter): scans kappa rows for b into LDS, then lane=t phi/window for its 256 t's.
__global__ __launch_bounds__(256) void k23_window(
    const float* __restrict__ abk_t,   // [30, BT] raw (kappa rows NOT pre-scanned)
    const float* __restrict__ kappa0,  // [B, K, 1]
    const float* __restrict__ ch,      // [B, U, V]
    float* __restrict__ out)           // [BT, 595]
{
    __shared__ float kap[KMIX][TT];      // 40 KB scanned kappa
    __shared__ float cst[VV][68];        // 21.8 KB char transposed
    __shared__ float win[4][UU * 81];    // 83 KB output staging (stride 81: odd -> conflict-free)
    const int b = blockIdx.x >> 2;
    const int qtr = blockIdx.x & 3;
    const int tid = threadIdx.x;
    const int wave = tid >> 6, lane = tid & 63;

    // Scan kappa_hat rows (full T, redundant across the 4 quarter-blocks; trivial work)
    for (int k = wave; k < KMIX; k += 4) {
        const float4* p4 = (const float4*)(abk_t + (size_t)(20 + k) * BT + b * TT);
        float v[16];
        #pragma unroll
        for (int i = 0; i < 4; ++i) {
            float4 q = p4[lane * 4 + i];
            v[i * 4] = q.x; v[i * 4 + 1] = q.y; v[i * 4 + 2] = q.z; v[i * 4 + 3] = q.w;
        }
        #pragma unroll
        for (int i = 1; i < 16; ++i) v[i] += v[i - 1];
        float total = v[15], xinc = total;
        #pragma unroll
        for (int off = 1; off < 64; off <<= 1) {
            float y = __shfl_up(xinc, off, 64);
            if (lane >= off) xinc += y;
        }
        float excl = xinc - total + kappa0[b * KMIX + k];
        float* kr = &kap[k][lane * 16];
        #pragma unroll
        for (int i = 0; i < 16; ++i) kr[i] = v[i] + excl;
    }

    // Stage char transposed
    const float4* c4 = (const float4*)(ch + (size_t)b * UU * VV);
    #pragma unroll
    for (int i = 0; i < 5; ++i) {
        int f4 = tid + i * 256;
        float4 v = c4[f4];
        int f = f4 * 4;
        int u = f / 80;
        int v0 = f - u * 80;
        cst[v0][u] = v.x; cst[v0 + 1][u] = v.y; cst[v0 + 2][u] = v.z; cst[v0 + 3][u] = v.w;
    }
    __syncthreads();

    const int tl = qtr * 256 + tid;      // t within b (tid = wave*64+lane)
    const int rbg = b * TT + tl;         // this lane's global row

    float ab[20];
    #pragma unroll
    for (int j = 0; j < 20; ++j) ab[j] = abk_t[(size_t)j * BT + rbg];  // coalesced
    float kp[KMIX];
    #pragma unroll
    for (int k = 0; k < KMIX; ++k) kp[k] = kap[k][tl];                 // consecutive lanes: conflict-free

    float phi[UU];
    #pragma unroll
    for (int u = 0; u < UU; ++u) {
        float s = 0.f;
        const float uf = (float)u;
        #pragma unroll
        for (int k = 0; k < KMIX; ++k) {
            float d = kp[k] - uf;
            s += ab[k] * __expf(-ab[10 + k] * d * d);
        }
        phi[u] = s;
    }

    float* winw = win[wave];
    for (int v = 0; v < VV; ++v) {
        float a = 0.f;
        #pragma unroll
        for (int q = 0; q < 16; ++q) {
            float4 cq = *(const float4*)&cst[v][q * 4];  // broadcast, shared by all 64 t's
            a += phi[q * 4] * cq.x + phi[q * 4 + 1] * cq.y
               + phi[q * 4 + 2] * cq.z + phi[q * 4 + 3] * cq.w;
        }
        winw[lane * 81 + v] = a;
    }

    // Coalesced flush (same wave: no barrier needed)
    const int rb = b * TT + qtr * 256 + wave * 64;
    for (int i = lane; i < UU * VV; i += 64) {
        int t = i / 80, v = i - t * 80;
        out[(size_t)(rb + t) * OUTW + HH + v] = winw[t * 81 + v];
    }
}

extern "C" void kernel_launch(void* const* d_in, const int* in_sizes, int n_in,
                              void* d_out, int out_size, void* d_ws, size_t ws_size,
                              hipStream_t stream) {
    const float* input0   = (const float*)d_in[0];
    const float* stroke   = (const float*)d_in[1];
    const float* chars    = (const float*)d_in[2];
    const float* window_w = (const float*)d_in[3];
    const float* window_b = (const float*)d_in[4];
    const float* kappa0   = (const float*)d_in[5];
    float* out   = (float*)d_out;
    float* abk_t = (float*)d_ws;                                     // [30][BT] = 7.86 MB
    float* Wt    = (float*)((char*)d_ws + (size_t)30 * BT * 4);      // [30][512] = 61 KB

    kW_transpose<<<dim3((30 * HH + 255) / 256), dim3(256), 0, stream>>>(window_w, Wt);
    k1_gemm<<<dim3(BT / ROWS), dim3(256), 0, stream>>>(input0, stroke, Wt, window_b, out, abk_t);
    k23_window<<<dim3(BB * 4), dim3(256), 0, stream>>>(abk_t, kappa0, chars, out);
}